// Round 1
// baseline (581.545 us; speedup 1.0000x reference)
//
#include <hip/hip_runtime.h>

// KPConv fused kernel for MI355X (gfx950).
// Shapes: N=50000 points, 32 neighbors, K=15 kernel pts, Cin=Cout=64, fp32 in/out.
// Strategy: per-point w[k][m] (VALU) -> stage1 MFMA (w @ x) -> LDS (swizzled) ->
// stage2 MFMA (weighted @ Wflat) -> fp32 out.  bf16 MFMA 16x16x32 throughout.

typedef __attribute__((ext_vector_type(8))) short bf16x8;
typedef __attribute__((ext_vector_type(4))) float f32x4;

#define NPTS        50000
#define PTS_PER_WG  16
#define KP_INV      (1.0f / 0.06f)

// fp32 -> bf16 round-to-nearest-even on raw bits (works for all finite values)
static __device__ __forceinline__ short f2bf(float f) {
    union { float f; unsigned u; } v; v.f = f;
    unsigned r = v.u + 0x7fffu + ((v.u >> 16) & 1u);
    return (short)(r >> 16);
}

__launch_bounds__(256, 4)
__global__ void kpconv_kernel(const float* __restrict__ q_pts,
                              const float* __restrict__ neighbors,
                              const float* __restrict__ x,
                              const float* __restrict__ kp,
                              const float* __restrict__ weights,
                              float* __restrict__ out) {
    // per-wave w buffer: rows k=0..15, cols m=0..31, padded to 40 elems (80 B)
    // so ds_read_b128 stays 16B-aligned and k/k+8 rows only 2-way alias (free).
    __shared__ __align__(16) unsigned short wa[4][640];
    // weighted (stage2 A operand), bf16, 16 points x 1024 K (k*64+c), chunk-XOR
    // swizzled by point so stage2 A-frag reads spread across banks.
    __shared__ __align__(16) unsigned short A2[PTS_PER_WG * 1024];

    const int tid   = threadIdx.x;
    const int wv    = tid >> 6;       // wave id 0..3
    const int lane  = tid & 63;
    const int quad  = lane >> 4;      // 0..3
    const int r16   = lane & 15;
    const int wg    = blockIdx.x;

    const int m32   = lane & 31;      // neighbor index for w-compute
    const int khalf = lane >> 5;      // 0/1

    // ================= stage 1: each wave handles 4 points =================
    for (int i = 0; i < 4; ++i) {
        const int  p = wv * 4 + i;
        const long n = (long)wg * PTS_PER_WG + p;

        // ---- geometry -> w[k][m32] (bf16 into wa[wv]) ----
        const float qx = q_pts[n*3 + 0];
        const float qy = q_pts[n*3 + 1];
        const float qz = q_pts[n*3 + 2];
        const float rx = neighbors[n*96 + m32*3 + 0] - qx;
        const float ry = neighbors[n*96 + m32*3 + 1] - qy;
        const float rz = neighbors[n*96 + m32*3 + 2] - qz;
        #pragma unroll
        for (int kk = 0; kk < 8; ++kk) {
            const int k  = kk * 2 + khalf;       // 0..15
            const int kc = (k < 15) ? k : 14;    // avoid OOB read of kernel_points
            const float dx = rx - kp[kc*3 + 0];
            const float dy = ry - kp[kc*3 + 1];
            const float dz = rz - kp[kc*3 + 2];
            float w = 1.0f - sqrtf(dx*dx + dy*dy + dz*dz) * KP_INV;
            w = (k < 15) ? fmaxf(w, 0.0f) : 0.0f;  // k=15 is zero padding
            wa[wv][k*40 + m32] = (unsigned short)f2bf(w);
        }
        __syncthreads();  // orders wa writes vs frag reads (uniform: all waves, 4 iters)

        // ---- A frag: w[k = r16][m = quad*8 + j] ----
        const bf16x8 af = *(const bf16x8*)&wa[wv][r16*40 + quad*8];

        // ---- 4 Cin tiles: B frag straight from global x, MFMA, spill to A2 ----
        const float* xp = x + n*2048 + (long)quad*512;   // + j*64 + c
        #pragma unroll
        for (int t = 0; t < 4; ++t) {
            const int c = t*16 + r16;
            bf16x8 bf;
            #pragma unroll
            for (int j = 0; j < 8; ++j) bf[j] = f2bf(xp[c + j*64]);
            f32x4 acc = {0.f, 0.f, 0.f, 0.f};
            acc = __builtin_amdgcn_mfma_f32_16x16x32_bf16(af, bf, acc, 0, 0, 0);
            // D layout: col c = lane&15 (+tile), row k = quad*4+reg
            #pragma unroll
            for (int reg = 0; reg < 4; ++reg) {
                const int k  = quad*4 + reg;
                const int k2 = k*64 + c;
                const int ch = k2 >> 3;
                A2[p*1024 + ((ch ^ (p & 7)) << 3) + (k2 & 7)]
                    = (unsigned short)f2bf(acc[reg]);
            }
        }
    }

    __syncthreads();  // all 16 points' weighted visible to all waves

    // ================= stage 2: out[16 pts][64] = weighted @ Wflat ==========
    // wave wv owns Cout tile [wv*16, wv*16+16); K loop over 960 (30 x 32).
    // weights[k][cin][cout] flattened is exactly [k2 = k*64+cin][cout].
    const int d = wv*16 + r16;
    f32x4 oacc = {0.f, 0.f, 0.f, 0.f};
    for (int kk = 0; kk < 30; ++kk) {
        // A frag: point row = r16, k2 = kk*32 + quad*8 + j  (chunk ch = kk*4+quad)
        const int ch = kk*4 + quad;
        const bf16x8 a2 = *(const bf16x8*)&A2[r16*1024 + ((ch ^ (r16 & 7)) << 3)];
        // B frag: weights[k2][d], j-strided dwords (L2-hot), cvt to bf16
        const float* wp = weights + (kk*32 + quad*8)*64 + d;
        bf16x8 bw;
        #pragma unroll
        for (int j = 0; j < 8; ++j) bw[j] = f2bf(wp[j*64]);
        oacc = __builtin_amdgcn_mfma_f32_16x16x32_bf16(a2, bw, oacc, 0, 0, 0);
    }

    // D layout: col d = lane&15 (+tile), row p = quad*4+reg
    #pragma unroll
    for (int reg = 0; reg < 4; ++reg) {
        const int p = quad*4 + reg;
        out[((long)wg * PTS_PER_WG + p)*64 + d] = oacc[reg];
    }
}

extern "C" void kernel_launch(void* const* d_in, const int* in_sizes, int n_in,
                              void* d_out, int out_size, void* d_ws, size_t ws_size,
                              hipStream_t stream) {
    // setup_inputs order: q_pts, s_pts, neighbors, neighb_inds, x, kernel_points, weights
    const float* q_pts     = (const float*)d_in[0];
    // d_in[1] s_pts      : unused by reference
    const float* neighbors = (const float*)d_in[2];
    // d_in[3] neighb_inds: unused by reference
    const float* x         = (const float*)d_in[4];
    const float* kp        = (const float*)d_in[5];
    const float* weights   = (const float*)d_in[6];
    float* out = (float*)d_out;

    dim3 grid(NPTS / PTS_PER_WG);   // 50000/16 = 3125, exact
    kpconv_kernel<<<grid, 256, 0, stream>>>(q_pts, neighbors, x, kp, weights, out);
}